// Round 2
// baseline (338.973 us; speedup 1.0000x reference)
//
#include <hip/hip_runtime.h>
#include <hip/hip_bf16.h>

typedef __attribute__((ext_vector_type(4))) float floatx4;
typedef __attribute__((ext_vector_type(8))) short shortx8;
typedef __attribute__((address_space(3))) void as3_void;
typedef const __attribute__((address_space(1))) void as1_void;

__device__ __forceinline__ unsigned short f2bf(float f) {
    unsigned int u; __builtin_memcpy(&u, &f, 4);
    u += 0x7FFFu + ((u >> 16) & 1u);   // RNE
    return (unsigned short)(u >> 16);
}
__device__ __forceinline__ float bf2f(unsigned short h) {
    unsigned int u = ((unsigned int)h) << 16;
    float f; __builtin_memcpy(&f, &u, 4); return f;
}
__device__ __forceinline__ shortx8 pack8(floatx4 lo, floatx4 hi) {
    shortx8 r;
    r[0] = (short)f2bf(lo[0]); r[1] = (short)f2bf(lo[1]);
    r[2] = (short)f2bf(lo[2]); r[3] = (short)f2bf(lo[3]);
    r[4] = (short)f2bf(hi[0]); r[5] = (short)f2bf(hi[1]);
    r[6] = (short)f2bf(hi[2]); r[7] = (short)f2bf(hi[3]);
    return r;
}
__device__ __forceinline__ void ld16(const unsigned short* g, unsigned short* l) {
    __builtin_amdgcn_global_load_lds((as1_void*)g, (as3_void*)l, 16, 0, 0);
}

// ---------- fp32 -> bf16 pre-convert (4 segments in one launch) ----------
__global__ __launch_bounds__(256) void cvt4(
    const float* __restrict__ s0, const float* __restrict__ s1,
    const float* __restrict__ s2, const float* __restrict__ s3,
    unsigned short* __restrict__ d0, unsigned short* __restrict__ d1,
    unsigned short* __restrict__ d2, unsigned short* __restrict__ d3,
    int nb0, int nb1, int nb2)
{
    int bid = blockIdx.x;
    const float* s; unsigned short* d;
    if (bid < nb0)                  { s = s0; d = d0; }
    else if (bid < nb0 + nb1)       { s = s1; d = d1; bid -= nb0; }
    else if (bid < nb0 + nb1 + nb2) { s = s2; d = d2; bid -= nb0 + nb1; }
    else                            { s = s3; d = d3; bid -= nb0 + nb1 + nb2; }
    const size_t i = ((size_t)bid * 256 + threadIdx.x) * 8;
    const floatx4 lo = *(const floatx4*)(s + i);
    const floatx4 hi = *(const floatx4*)(s + i + 4);
    *(shortx8*)(d + i) = pack8(lo, hi);
}

// ---------- 256x256 8-phase GEMM (T1+T2+T3+T4+T5) ----------
// C[25088 x 2304] = Xb[25088 x 768] * Wb[2304 x 768]^T, N folded over q/k/v.
// 8 waves (2M x 4N), per-wave 128x64 out. BK=64, 2 LDS dbufs (128 KiB).
// 4 phases per K-tile: {reads+stage; s_barrier; lgkmcnt(0); 16 MFMA; s_barrier}.
// Tile t's ph2/ph3 stage tile t+2 into dbuf(t) (regions dead after ph1/ph2
// trailing barriers). End-of-tile wait = vmcnt(8): the 8 newest outstanding
// loads are tile t+2's, so everything for t+1 has landed. Never vmcnt(0)
// in steady state; raw s_barrier (no __syncthreads -> no forced drain).
// T2: elem ^= (row&7)<<3 swizzle; staged via pre-swizzled GLOBAL source
// (linear LDS dest, rule 21) and applied on ds_read -> 2-way (free) banks.
__global__ __launch_bounds__(512, 2) void gemm_qkv_8ph(
    const unsigned short* __restrict__ Xb,
    const unsigned short* __restrict__ Wb,   // 3 contiguous 768x768 = 2304x768
    const float* __restrict__ bq, const float* __restrict__ bk,
    const float* __restrict__ bv,
    float* __restrict__ Qf, unsigned short* __restrict__ Qb16,
    unsigned short* __restrict__ Kb, unsigned short* __restrict__ Vb)
{
    constexpr int K  = 768;
    constexpr int NT = 12;               // K / 64
    __shared__ __attribute__((aligned(16))) unsigned short As[2][16384];
    __shared__ __attribute__((aligned(16))) unsigned short Bs[2][16384];

    // bijective XCD swizzle for 882 blocks (m204: q=110, r=2), y-grouped so
    // the 9 n-tiles sharing an A-panel land on the same XCD.
    const unsigned orig = blockIdx.x;                 // 0..881
    const unsigned xcd  = orig & 7u, loc = orig >> 3;
    const unsigned wg   = (xcd < 2u ? xcd * 111u : 222u + (xcd - 2u) * 110u) + loc;
    const unsigned yb   = wg / 9u;                    // 0..97
    const unsigned nb   = wg - yb * 9u;               // 0..8

    const int tid  = threadIdx.x;
    const int wave = tid >> 6, lane = tid & 63;
    const int fRow = lane & 15, gq = lane >> 4;
    const int wm = (wave >> 2) * 128;                 // 0 / 128
    const int wn = (wave & 3) * 64;                   // 0 / 64 / 128 / 192
    const int mBlock = (int)yb * 256;
    const int nRow0  = (int)nb * 256;

    // ---- staging: linear LDS dest (tid*16B), pre-swizzled global source ----
    const int srow = tid >> 3;                          // 0..63
    const int scol = 8 * ((tid & 7) ^ (srow & 7));      // inverse of read swz
    int aOff[4], bOff[4];
    #pragma unroll
    for (int rr = 0; rr < 4; rr++) {
        aOff[rr] = (mBlock + rr * 64 + srow) * K + scol;
        bOff[rr] = (nRow0  + rr * 64 + srow) * K + scol;
    }
    auto stageA_ = [&](int tile) {
        unsigned short* d = &As[tile & 1][tid * 8];
        const unsigned short* s = Xb + tile * 64;
        #pragma unroll
        for (int rr = 0; rr < 4; rr++) ld16(s + aOff[rr], d + rr * 4096);
    };
    auto stageB_ = [&](int tile) {
        unsigned short* d = &Bs[tile & 1][tid * 8];
        const unsigned short* s = Wb + tile * 64;
        #pragma unroll
        for (int rr = 0; rr < 4; rr++) ld16(s + bOff[rr], d + rr * 4096);
    };

    // ---- ds_read addressing (swizzled) ----
    const int colSwz0 = (gq * 8)      ^ ((fRow & 7) << 3);   // kslot 0
    const int colSwz1 = (32 + gq * 8) ^ ((fRow & 7) << 3);   // kslot 1
    const int rowA = (wm + fRow) * 64;
    const int rowB = (wn + fRow) * 64;

    floatx4 acc[8][4] = {};
    shortx8 aF[4][2], bF[4][2];

    // ---- prologue: stage tiles 0 and 1 (16 loads); wait tile0 only ----
    stageB_(0); stageA_(0); stageB_(1); stageA_(1);
    asm volatile("s_waitcnt vmcnt(8)" ::: "memory");
    __builtin_amdgcn_s_barrier();

    for (int t = 0; t < NT; ++t) {
        const int db = t & 1;
        const unsigned short* A0 = &As[db][rowA];
        const unsigned short* B0 = &Bs[db][rowB];

        // ===== phase 0: A frags 0-3 + B frags 0-1 (12 reads); q(m0-3,n0-1)
        #pragma unroll
        for (int i = 0; i < 4; i++) {
            aF[i][0] = *(const shortx8*)&A0[i * 1024 + colSwz0];
            aF[i][1] = *(const shortx8*)&A0[i * 1024 + colSwz1];
        }
        #pragma unroll
        for (int n = 0; n < 2; n++) {
            bF[n][0] = *(const shortx8*)&B0[n * 1024 + colSwz0];
            bF[n][1] = *(const shortx8*)&B0[n * 1024 + colSwz1];
        }
        __builtin_amdgcn_s_barrier();
        asm volatile("s_waitcnt lgkmcnt(0)" ::: "memory");
        __builtin_amdgcn_s_setprio(1);
        #pragma unroll
        for (int i = 0; i < 4; i++)
            #pragma unroll
            for (int n = 0; n < 2; n++) {
                acc[i][n] = __builtin_amdgcn_mfma_f32_16x16x32_bf16(aF[i][0], bF[n][0], acc[i][n], 0, 0, 0);
                acc[i][n] = __builtin_amdgcn_mfma_f32_16x16x32_bf16(aF[i][1], bF[n][1], acc[i][n], 0, 0, 0);
            }
        __builtin_amdgcn_s_setprio(0);
        __builtin_amdgcn_s_barrier();

        // ===== phase 1: B frags 2-3 (4 reads); q(m0-3,n2-3)
        #pragma unroll
        for (int n = 2; n < 4; n++) {
            bF[n][0] = *(const shortx8*)&B0[n * 1024 + colSwz0];
            bF[n][1] = *(const shortx8*)&B0[n * 1024 + colSwz1];
        }
        __builtin_amdgcn_s_barrier();
        asm volatile("s_waitcnt lgkmcnt(0)" ::: "memory");
        __builtin_amdgcn_s_setprio(1);
        #pragma unroll
        for (int i = 0; i < 4; i++)
            #pragma unroll
            for (int n = 2; n < 4; n++) {
                acc[i][n] = __builtin_amdgcn_mfma_f32_16x16x32_bf16(aF[i][0], bF[n][0], acc[i][n], 0, 0, 0);
                acc[i][n] = __builtin_amdgcn_mfma_f32_16x16x32_bf16(aF[i][1], bF[n][1], acc[i][n], 0, 0, 0);
            }
        __builtin_amdgcn_s_setprio(0);
        __builtin_amdgcn_s_barrier();
        // B(t) reads drained before this barrier -> B region of dbuf is dead.

        // ===== phase 2: A frags 4-7 (8 reads); stage B(t+2); q(m4-7,n0-1)
        #pragma unroll
        for (int i = 0; i < 4; i++) {
            aF[i][0] = *(const shortx8*)&A0[(i + 4) * 1024 + colSwz0];
            aF[i][1] = *(const shortx8*)&A0[(i + 4) * 1024 + colSwz1];
        }
        if (t + 2 < NT) stageB_(t + 2);
        __builtin_amdgcn_s_barrier();
        asm volatile("s_waitcnt lgkmcnt(0)" ::: "memory");
        __builtin_amdgcn_s_setprio(1);
        #pragma unroll
        for (int i = 0; i < 4; i++)
            #pragma unroll
            for (int n = 0; n < 2; n++) {
                acc[4 + i][n] = __builtin_amdgcn_mfma_f32_16x16x32_bf16(aF[i][0], bF[n][0], acc[4 + i][n], 0, 0, 0);
                acc[4 + i][n] = __builtin_amdgcn_mfma_f32_16x16x32_bf16(aF[i][1], bF[n][1], acc[4 + i][n], 0, 0, 0);
            }
        __builtin_amdgcn_s_setprio(0);
        __builtin_amdgcn_s_barrier();
        // A(t) reads drained -> A region of dbuf is dead.

        // ===== phase 3: stage A(t+2); q(m4-7,n2-3); counted vmcnt; barrier
        if (t + 2 < NT) stageA_(t + 2);
        __builtin_amdgcn_s_barrier();
        asm volatile("s_waitcnt lgkmcnt(0)" ::: "memory");
        __builtin_amdgcn_s_setprio(1);
        #pragma unroll
        for (int i = 0; i < 4; i++)
            #pragma unroll
            for (int n = 2; n < 4; n++) {
                acc[4 + i][n] = __builtin_amdgcn_mfma_f32_16x16x32_bf16(aF[i][0], bF[n][0], acc[4 + i][n], 0, 0, 0);
                acc[4 + i][n] = __builtin_amdgcn_mfma_f32_16x16x32_bf16(aF[i][1], bF[n][1], acc[4 + i][n], 0, 0, 0);
            }
        __builtin_amdgcn_s_setprio(0);
        if (t + 2 < NT)      { asm volatile("s_waitcnt vmcnt(8)" ::: "memory"); }
        else if (t + 1 < NT) { asm volatile("s_waitcnt vmcnt(0)" ::: "memory"); }
        __builtin_amdgcn_s_barrier();
        // after this barrier, every wave's tile t+1 data has landed.
    }

    // ---- epilogue: C/D layout col=lane&15, row=(lane>>4)*4+reg ----
    const int z     = (int)nb / 3;
    const int colZ0 = ((int)nb - z * 3) * 256 + wn;
    const float* bias = (z == 0) ? bq : ((z == 1) ? bk : bv);
    if (z == 0 && Qb16 == nullptr) {
        #pragma unroll
        for (int n = 0; n < 4; n++) {
            const int col = colZ0 + n * 16 + fRow;
            const float bvf = bias[col];
            #pragma unroll
            for (int i = 0; i < 8; i++)
                #pragma unroll
                for (int r = 0; r < 4; r++)
                    Qf[(size_t)(mBlock + wm + i * 16 + gq * 4 + r) * 768 + col] =
                        acc[i][n][r] + bvf;
        }
    } else {
        unsigned short* Out = (z == 0) ? Qb16 : ((z == 1) ? Kb : Vb);
        #pragma unroll
        for (int n = 0; n < 4; n++) {
            const int col = colZ0 + n * 16 + fRow;
            const float bvf = bias[col];
            #pragma unroll
            for (int i = 0; i < 8; i++)
                #pragma unroll
                for (int r = 0; r < 4; r++)
                    Out[(size_t)(mBlock + wm + i * 16 + gq * 4 + r) * 768 + col] =
                        f2bf(acc[i][n][r] + bvf);
        }
    }
}

#define BM 128
#define BN 128
#define BK 32

// ---------- fallback GEMM (round-3 proven): fp32 src, pack in kernel ----------
__global__ __launch_bounds__(256) void gemm_qkv_f32(
    const float* __restrict__ X,
    const float* __restrict__ Wq, const float* __restrict__ Wk,
    const float* __restrict__ Wv,
    const float* __restrict__ bq, const float* __restrict__ bk,
    const float* __restrict__ bv,
    float* __restrict__ Qf, unsigned short* __restrict__ Kb,
    unsigned short* __restrict__ Vb,
    int M, int N, int K)
{
    __shared__ __attribute__((aligned(16))) unsigned short As[BM * BK];
    __shared__ __attribute__((aligned(16))) unsigned short Bs[BN * BK];

    const float* W;  const float* bias;
    if (blockIdx.z == 0)      { W = Wq; bias = bq; }
    else if (blockIdx.z == 1) { W = Wk; bias = bk; }
    else                      { W = Wv; bias = bv; }

    const int tid  = threadIdx.x;
    const int wave = tid >> 6;
    const int lane = tid & 63;
    const int mBlock = blockIdx.y * BM;
    const int nBlock = blockIdx.x * BN;

    const int sRow = tid >> 1;
    const int sCol = (tid & 1) * 16;
    const float* Ag = X + (size_t)(mBlock + sRow) * K + sCol;
    const float* Bg = W + (size_t)(nBlock + sRow) * K + sCol;
    unsigned short* Al = &As[sRow * BK + sCol];
    unsigned short* Bl = &Bs[sRow * BK + sCol];

    floatx4 acc[4][4] = {};
    const int wm   = (wave >> 1) * 64;
    const int wn   = (wave & 1) * 64;
    const int fRow = lane & 15;
    const int fK   = (lane >> 4) * 8;

    for (int kt = 0; kt < K; kt += BK) {
        floatx4 a[4], b[4];
        #pragma unroll
        for (int c = 0; c < 4; c++) {
            a[c] = *(const floatx4*)(Ag + kt + c * 4);
            b[c] = *(const floatx4*)(Bg + kt + c * 4);
        }
        __syncthreads();
        *(shortx8*)(Al)     = pack8(a[0], a[1]);
        *(shortx8*)(Al + 8) = pack8(a[2], a[3]);
        *(shortx8*)(Bl)     = pack8(b[0], b[1]);
        *(shortx8*)(Bl + 8) = pack8(b[2], b[3]);
        __syncthreads();

        shortx8 af[4], bfr[4];
        #pragma unroll
        for (int i = 0; i < 4; i++) {
            af[i]  = *(const shortx8*)&As[(wm + i*16 + fRow) * BK + fK];
            bfr[i] = *(const shortx8*)&Bs[(wn + i*16 + fRow) * BK + fK];
        }
        #pragma unroll
        for (int i = 0; i < 4; i++)
            #pragma unroll
            for (int j = 0; j < 4; j++)
                acc[i][j] = __builtin_amdgcn_mfma_f32_16x16x32_bf16(
                    af[i], bfr[j], acc[i][j], 0, 0, 0);
    }

    const int cRow = (lane >> 4) * 4;
    const int cCol = lane & 15;
    if (blockIdx.z == 0) {
        #pragma unroll
        for (int j = 0; j < 4; j++) {
            const int col = nBlock + wn + j*16 + cCol;
            const float bvf = bias[col];
            #pragma unroll
            for (int i = 0; i < 4; i++)
                #pragma unroll
                for (int r = 0; r < 4; r++)
                    Qf[(size_t)(mBlock + wm + i*16 + cRow + r) * N + col] =
                        acc[i][j][r] + bvf;
        }
    } else {
        unsigned short* Out = (blockIdx.z == 1) ? Kb : Vb;
        #pragma unroll
        for (int j = 0; j < 4; j++) {
            const int col = nBlock + wn + j*16 + cCol;
            const float bvf = bias[col];
            #pragma unroll
            for (int i = 0; i < 4; i++)
                #pragma unroll
                for (int r = 0; r < 4; r++)
                    Out[(size_t)(mBlock + wm + i*16 + cRow + r) * N + col] =
                        f2bf(acc[i][j][r] + bvf);
        }
    }
}

// ---------- sampler: one wave per (b,p), XCD-clustered b mapping ----------
__global__ __launch_bounds__(64) void sample_attend(
    const float* __restrict__ Qf,            // fp32 q (if Qb16 == null)
    const unsigned short* __restrict__ Qb16, // bf16 q (preferred)
    const unsigned short* __restrict__ Kb,
    const unsigned short* __restrict__ Vb,
    const float* __restrict__ normx,
    const float* __restrict__ normy,
    const int* __restrict__ img_ids,
    const float* __restrict__ avgs,
    const float* __restrict__ stds,
    float* __restrict__ out)
{
    const unsigned g    = blockIdx.x;
    const unsigned xcd  = g & 7;
    const unsigned slot = g >> 3;            // 0..3135
    const int b = (int)(xcd * 16 + slot / 196);
    const int p = (int)(slot % 196);
    const int lane = threadIdx.x;
    const int id = img_ids[b];

    // grid flat = [sx(196), sy(196)]: gx = flat[2p], gy = flat[2p+1]
    auto coord = [&](int n) -> float {
        int c = 0;
        if (n >= 196) { n -= 196; c = 1; }
        const float base = (c == 0) ? normx[b*196 + n] : normy[b*196 + n];
        const float a = avgs[(size_t)id*392 + c*196 + n];
        const float s = stds[(size_t)id*392 + c*196 + n];
        return tanhf((base + a) * s);
    };
    const float gx = coord(2*p);
    const float gy = coord(2*p + 1);

    const float ix = ((gx + 1.0f) * 14.0f - 1.0f) * 0.5f;
    const float iy = ((gy + 1.0f) * 14.0f - 1.0f) * 0.5f;
    const float x0f = floorf(ix), y0f = floorf(iy);
    const float wx1 = ix - x0f, wx0 = 1.0f - wx1;
    const float wy1 = iy - y0f, wy0 = 1.0f - wy1;
    const int x0 = (int)x0f, y0 = (int)y0f;

    float cw[4]; int rr[4];
    {
        const int xs[4] = {x0, x0+1, x0, x0+1};
        const int ys[4] = {y0, y0, y0+1, y0+1};
        const float ws4[4] = {wx0*wy0, wx1*wy0, wx0*wy1, wx1*wy1};
        #pragma unroll
        for (int c = 0; c < 4; c++) {
            const bool valid = xs[c] >= 0 && xs[c] <= 13 && ys[c] >= 0 && ys[c] <= 13;
            cw[c] = valid ? ws4[c] : 0.0f;
            rr[c] = valid ? (ys[c]*14 + xs[c]) * 768 : 0;
        }
    }

    const size_t rowOff = ((size_t)b*196 + p) * 768;
    const unsigned short* kb = Kb + (size_t)b * 196 * 768;
    const unsigned short* vb = Vb + (size_t)b * 196 * 768;

    floatx4 pv[3];
    float partial = 0.0f;
    #pragma unroll
    for (int j = 0; j < 3; j++) {
        const int d = lane * 4 + j * 256;        // 4 elems / lane / j
        floatx4 kx = {0.f, 0.f, 0.f, 0.f}, vx = {0.f, 0.f, 0.f, 0.f};
        #pragma unroll
        for (int c = 0; c < 4; c++) {
            const unsigned long long kw = *(const unsigned long long*)&kb[rr[c] + d];
            const unsigned long long vw = *(const unsigned long long*)&vb[rr[c] + d];
            #pragma unroll
            for (int e = 0; e < 4; e++) {
                kx[e] += cw[c] * bf2f((unsigned short)(kw >> (16*e)));
                vx[e] += cw[c] * bf2f((unsigned short)(vw >> (16*e)));
            }
        }
        floatx4 q4;
        if (Qb16 != nullptr) {
            const unsigned long long qw = *(const unsigned long long*)&Qb16[rowOff + d];
            q4[0] = bf2f((unsigned short)qw);
            q4[1] = bf2f((unsigned short)(qw >> 16));
            q4[2] = bf2f((unsigned short)(qw >> 32));
            q4[3] = bf2f((unsigned short)(qw >> 48));
        } else {
            q4 = *(const floatx4*)&Qf[rowOff + d];
        }
        partial += kx[0]*q4[0] + kx[1]*q4[1] + kx[2]*q4[2] + kx[3]*q4[3];
        pv[j] = vx;
    }

    #pragma unroll
    for (int off = 32; off >= 1; off >>= 1)
        partial += __shfl_xor(partial, off, 64);
    const float sig = 1.0f / (1.0f + expf(-0.01f * partial));

    #pragma unroll
    for (int j = 0; j < 3; j++) {
        floatx4 o;
        o[0] = sig * pv[j][0]; o[1] = sig * pv[j][1];
        o[2] = sig * pv[j][2]; o[3] = sig * pv[j][3];
        *(floatx4*)&out[rowOff + lane * 4 + j * 256] = o;
    }
}

extern "C" void kernel_launch(void* const* d_in, const int* in_sizes, int n_in,
                              void* d_out, int out_size, void* d_ws, size_t ws_size,
                              hipStream_t stream) {
    const float* x     = (const float*)d_in[0];
    const int*   ids   = (const int*)d_in[1];
    // d_in[2] = mask (unused by reference)
    const float* normx = (const float*)d_in[3];
    const float* normy = (const float*)d_in[4];
    const float* Wq    = (const float*)d_in[5];
    const float* bq    = (const float*)d_in[6];
    const float* Wk    = (const float*)d_in[7];
    const float* bk    = (const float*)d_in[8];
    const float* Wv    = (const float*)d_in[9];
    const float* bv    = (const float*)d_in[10];
    const float* avgs  = (const float*)d_in[11];
    const float* stds  = (const float*)d_in[12];
    float* out = (float*)d_out;

    const int B = 128, P = 196, D = 768;
    const int M = B * P;                         // 25088
    const size_t qkvElems = (size_t)M * D;       // 19,267,584
    const size_t wElems   = (size_t)D * D;       // 589,824

    // ws tiers (deterministic: ws_size constant across calls)
    const size_t tierA = (4 * qkvElems + 3 * wElems) * 2;  // +bf16 q  (~157.7 MB)
    const size_t tierB = (3 * qkvElems + 3 * wElems) * 2;  // bf16 X/W/k/v (~119 MB)

    const int nSampBlocks = 8 * 16 * P;          // 25088

    if (ws_size >= tierB) {
        unsigned short* Xb = (unsigned short*)d_ws;
        unsigned short* Wb = Xb + qkvElems;
        unsigned short* k  = Wb + 3 * wElems;
        unsigned short* v  = k + qkvElems;
        unsigned short* qb = (ws_size >= tierA) ? (v + qkvElems) : nullptr;
        float* qf = (qb == nullptr) ? out : nullptr;

        const int nbX = (int)(qkvElems / 8 / 256);   // 9408
        const int nbW = (int)(wElems / 8 / 256);     // 288
        cvt4<<<nbX + 3 * nbW, 256, 0, stream>>>(
            x, Wq, Wk, Wv, Xb, Wb, Wb + wElems, Wb + 2 * wElems, nbX, nbW, nbW);

        // 256x256 tiles over M=25088 (98) x N=2304 (9) -> 882 blocks
        gemm_qkv_8ph<<<882, 512, 0, stream>>>(
            Xb, Wb, bq, bk, bv, qf, qb, k, v);

        sample_attend<<<nSampBlocks, 64, 0, stream>>>(
            qf, qb, k, v, normx, normy, ids, avgs, stds, out);
    } else {
        unsigned short* k = (unsigned short*)d_ws;
        unsigned short* v = k + qkvElems;

        dim3 gGemm(D / BN, M / BM, 3);
        gemm_qkv_f32<<<gGemm, 256, 0, stream>>>(
            x, Wq, Wk, Wv, bq, bk, bv, out, k, v, M, D, D);

        sample_attend<<<nSampBlocks, 64, 0, stream>>>(
            out, nullptr, k, v, normx, normy, ids, avgs, stds, out);
    }
}

// Round 3
// 334.292 us; speedup vs baseline: 1.0140x; 1.0140x over previous
//
#include <hip/hip_runtime.h>
#include <hip/hip_bf16.h>

typedef __attribute__((ext_vector_type(4))) float floatx4;
typedef __attribute__((ext_vector_type(8))) short shortx8;
typedef __attribute__((address_space(3))) void as3_void;
typedef const __attribute__((address_space(1))) void as1_void;

__device__ __forceinline__ unsigned short f2bf(float f) {
    unsigned int u; __builtin_memcpy(&u, &f, 4);
    u += 0x7FFFu + ((u >> 16) & 1u);   // RNE
    return (unsigned short)(u >> 16);
}
__device__ __forceinline__ float bf2f(unsigned short h) {
    unsigned int u = ((unsigned int)h) << 16;
    float f; __builtin_memcpy(&f, &u, 4); return f;
}
__device__ __forceinline__ shortx8 pack8(floatx4 lo, floatx4 hi) {
    shortx8 r;
    r[0] = (short)f2bf(lo[0]); r[1] = (short)f2bf(lo[1]);
    r[2] = (short)f2bf(lo[2]); r[3] = (short)f2bf(lo[3]);
    r[4] = (short)f2bf(hi[0]); r[5] = (short)f2bf(hi[1]);
    r[6] = (short)f2bf(hi[2]); r[7] = (short)f2bf(hi[3]);
    return r;
}
__device__ __forceinline__ void ld16(const unsigned short* g, unsigned short* l) {
    __builtin_amdgcn_global_load_lds((as1_void*)g, (as3_void*)l, 16, 0, 0);
}

#define BM 128
#define BN 128
#define BK 32

// ---------- fp32 -> bf16 pre-convert (4 segments in one launch) ----------
__global__ __launch_bounds__(256) void cvt4(
    const float* __restrict__ s0, const float* __restrict__ s1,
    const float* __restrict__ s2, const float* __restrict__ s3,
    unsigned short* __restrict__ d0, unsigned short* __restrict__ d1,
    unsigned short* __restrict__ d2, unsigned short* __restrict__ d3,
    int nb0, int nb1, int nb2)
{
    int bid = blockIdx.x;
    const float* s; unsigned short* d;
    if (bid < nb0)                  { s = s0; d = d0; }
    else if (bid < nb0 + nb1)       { s = s1; d = d1; bid -= nb0; }
    else if (bid < nb0 + nb1 + nb2) { s = s2; d = d2; bid -= nb0 + nb1; }
    else                            { s = s3; d = d3; bid -= nb0 + nb1 + nb2; }
    const size_t i = ((size_t)bid * 256 + threadIdx.x) * 8;
    const floatx4 lo = *(const floatx4*)(s + i);
    const floatx4 hi = *(const floatx4*)(s + i + 4);
    *(shortx8*)(d + i) = pack8(lo, hi);
}

// ---------- fast GEMM (round-1 proven, 143us): m97 structure + y-grouped
// XCD swizzle + K-unroll2. q/k/v = Xb (MxK bf16) * Wb[z]^T (NxK bf16) + bias.
// Grid is 1D (6*196*3 = 3528 = 8*441 blocks). blockIdx%8 = XCD; each XCD owns
// contiguous y-groups so the 18 blocks sharing an A-tile run on ONE XCD ->
// A-tile L2-hit instead of HBM once per XCD (FETCH 360->121 MB measured).
__global__ __launch_bounds__(256) void gemm_qkv_bf16(
    const unsigned short* __restrict__ Xb,
    const unsigned short* __restrict__ Wb,   // 3 contiguous NxK mats
    const float* __restrict__ bq, const float* __restrict__ bk,
    const float* __restrict__ bv,
    float* __restrict__ Qf, unsigned short* __restrict__ Qb16,
    unsigned short* __restrict__ Kb, unsigned short* __restrict__ Vb,
    int M, int N, int K)
{
    __shared__ __attribute__((aligned(16))) unsigned short As[2 * BM * BK];
    __shared__ __attribute__((aligned(16))) unsigned short Bs[2 * BN * BK];

    // swizzled decode: w = y*18 + z*6 + x, chunked 441-per-XCD (bijective)
    const unsigned g    = blockIdx.x;
    const unsigned xcd  = g & 7u;
    const unsigned slot = g >> 3;                 // 0..440
    const unsigned w    = xcd * 441u + slot;      // y-grouped work index
    const unsigned yb   = w / 18u;                // M-tile 0..195
    const unsigned rr_  = w - yb * 18u;
    const unsigned z    = rr_ / 6u;               // 0..2
    const unsigned xb   = rr_ - z * 6u;           // N-tile 0..5

    const unsigned short* W = Wb + (size_t)z * N * K;
    const float* bias = (z == 0) ? bq : ((z == 1) ? bk : bv);

    const int tid  = threadIdx.x;
    const int wave = tid >> 6;
    const int lane = tid & 63;

    const int mBlock = (int)yb * BM;
    const int nBlock = (int)xb * BN;

    // staging: thread t -> row t>>2 (and +64), 8-elem chunk (t&3)*8.
    const int sRow   = tid >> 2;
    const int sChunk = (tid & 3) * 8;
    const unsigned short* Ag = Xb + (size_t)(mBlock + sRow) * K + sChunk;
    const unsigned short* Bg = W  + (size_t)(nBlock + sRow) * K + sChunk;
    unsigned short* Al = &As[sRow * BK + sChunk];
    unsigned short* Bl = &Bs[sRow * BK + sChunk];

    floatx4 acc[4][4] = {};

    const int wm   = (wave >> 1) * 64;
    const int wn   = (wave & 1) * 64;
    const int fRow = lane & 15;
    const int fK   = (lane >> 4) * 8;

    for (int kt = 0; kt < K; kt += 2 * BK) {
        // chunk 0 (k = kt)
        ld16(Ag + kt,                      Al);
        ld16(Ag + kt + (size_t)64*K,       Al + 64 * BK);
        ld16(Bg + kt,                      Bl);
        ld16(Bg + kt + (size_t)64*K,       Bl + 64 * BK);
        // chunk 1 (k = kt + 32)
        ld16(Ag + kt + BK,                 Al + BM * BK);
        ld16(Ag + kt + BK + (size_t)64*K,  Al + BM * BK + 64 * BK);
        ld16(Bg + kt + BK,                 Bl + BN * BK);
        ld16(Bg + kt + BK + (size_t)64*K,  Bl + BN * BK + 64 * BK);
        __syncthreads();                    // drains vmcnt before barrier

        #pragma unroll
        for (int c = 0; c < 2; c++) {
            const unsigned short* Asc = As + c * BM * BK;
            const unsigned short* Bsc = Bs + c * BN * BK;
            shortx8 af[4], bfr[4];
            #pragma unroll
            for (int i = 0; i < 4; i++) {
                af[i]  = *(const shortx8*)&Asc[(wm + i*16 + fRow) * BK + fK];
                bfr[i] = *(const shortx8*)&Bsc[(wn + i*16 + fRow) * BK + fK];
            }
            #pragma unroll
            for (int i = 0; i < 4; i++)
                #pragma unroll
                for (int j = 0; j < 4; j++)
                    acc[i][j] = __builtin_amdgcn_mfma_f32_16x16x32_bf16(
                        af[i], bfr[j], acc[i][j], 0, 0, 0);
        }
        __syncthreads();                    // LDS reads done before next stage
    }

    // C/D layout: col = lane&15, row = (lane>>4)*4 + reg
    const int cRow = (lane >> 4) * 4;
    const int cCol = lane & 15;
    if (z == 0 && Qb16 == nullptr) {
        #pragma unroll
        for (int j = 0; j < 4; j++) {
            const int col = nBlock + wn + j*16 + cCol;
            const float bvf = bias[col];
            #pragma unroll
            for (int i = 0; i < 4; i++)
                #pragma unroll
                for (int r = 0; r < 4; r++)
                    Qf[(size_t)(mBlock + wm + i*16 + cRow + r) * N + col] =
                        acc[i][j][r] + bvf;
        }
    } else {
        unsigned short* Out = (z == 0) ? Qb16 : ((z == 1) ? Kb : Vb);
        #pragma unroll
        for (int j = 0; j < 4; j++) {
            const int col = nBlock + wn + j*16 + cCol;
            const float bvf = bias[col];
            #pragma unroll
            for (int i = 0; i < 4; i++)
                #pragma unroll
                for (int r = 0; r < 4; r++)
                    Out[(size_t)(mBlock + wm + i*16 + cRow + r) * N + col] =
                        f2bf(acc[i][j][r] + bvf);
        }
    }
}

// ---------- fallback GEMM (round-3 proven): fp32 src, pack in kernel ----------
__global__ __launch_bounds__(256) void gemm_qkv_f32(
    const float* __restrict__ X,
    const float* __restrict__ Wq, const float* __restrict__ Wk,
    const float* __restrict__ Wv,
    const float* __restrict__ bq, const float* __restrict__ bk,
    const float* __restrict__ bv,
    float* __restrict__ Qf, unsigned short* __restrict__ Kb,
    unsigned short* __restrict__ Vb,
    int M, int N, int K)
{
    __shared__ __attribute__((aligned(16))) unsigned short As[BM * BK];
    __shared__ __attribute__((aligned(16))) unsigned short Bs[BN * BK];

    const float* W;  const float* bias;
    if (blockIdx.z == 0)      { W = Wq; bias = bq; }
    else if (blockIdx.z == 1) { W = Wk; bias = bk; }
    else                      { W = Wv; bias = bv; }

    const int tid  = threadIdx.x;
    const int wave = tid >> 6;
    const int lane = tid & 63;
    const int mBlock = blockIdx.y * BM;
    const int nBlock = blockIdx.x * BN;

    const int sRow = tid >> 1;
    const int sCol = (tid & 1) * 16;
    const float* Ag = X + (size_t)(mBlock + sRow) * K + sCol;
    const float* Bg = W + (size_t)(nBlock + sRow) * K + sCol;
    unsigned short* Al = &As[sRow * BK + sCol];
    unsigned short* Bl = &Bs[sRow * BK + sCol];

    floatx4 acc[4][4] = {};
    const int wm   = (wave >> 1) * 64;
    const int wn   = (wave & 1) * 64;
    const int fRow = lane & 15;
    const int fK   = (lane >> 4) * 8;

    for (int kt = 0; kt < K; kt += BK) {
        floatx4 a[4], b[4];
        #pragma unroll
        for (int c = 0; c < 4; c++) {
            a[c] = *(const floatx4*)(Ag + kt + c * 4);
            b[c] = *(const floatx4*)(Bg + kt + c * 4);
        }
        __syncthreads();
        *(shortx8*)(Al)     = pack8(a[0], a[1]);
        *(shortx8*)(Al + 8) = pack8(a[2], a[3]);
        *(shortx8*)(Bl)     = pack8(b[0], b[1]);
        *(shortx8*)(Bl + 8) = pack8(b[2], b[3]);
        __syncthreads();

        shortx8 af[4], bfr[4];
        #pragma unroll
        for (int i = 0; i < 4; i++) {
            af[i]  = *(const shortx8*)&As[(wm + i*16 + fRow) * BK + fK];
            bfr[i] = *(const shortx8*)&Bs[(wn + i*16 + fRow) * BK + fK];
        }
        #pragma unroll
        for (int i = 0; i < 4; i++)
            #pragma unroll
            for (int j = 0; j < 4; j++)
                acc[i][j] = __builtin_amdgcn_mfma_f32_16x16x32_bf16(
                    af[i], bfr[j], acc[i][j], 0, 0, 0);
    }

    const int cRow = (lane >> 4) * 4;
    const int cCol = lane & 15;
    if (blockIdx.z == 0) {
        #pragma unroll
        for (int j = 0; j < 4; j++) {
            const int col = nBlock + wn + j*16 + cCol;
            const float bvf = bias[col];
            #pragma unroll
            for (int i = 0; i < 4; i++)
                #pragma unroll
                for (int r = 0; r < 4; r++)
                    Qf[(size_t)(mBlock + wm + i*16 + cRow + r) * N + col] =
                        acc[i][j][r] + bvf;
        }
    } else {
        unsigned short* Out = (blockIdx.z == 1) ? Kb : Vb;
        #pragma unroll
        for (int j = 0; j < 4; j++) {
            const int col = nBlock + wn + j*16 + cCol;
            const float bvf = bias[col];
            #pragma unroll
            for (int i = 0; i < 4; i++)
                #pragma unroll
                for (int r = 0; r < 4; r++)
                    Out[(size_t)(mBlock + wm + i*16 + cRow + r) * N + col] =
                        f2bf(acc[i][j][r] + bvf);
        }
    }
}

// ---------- sampler v2: 4 waves/block (one p per wave) ----------
// v1 used 64-thread workgroups: CU workgroup-slot cap (~16 wg/CU) limits
// residency to ~16 waves/CU = half the latency-hiding budget on a kernel
// that is pure scattered-load latency. v2: 256-thread blocks (4 waves = 4
// consecutive p of the same b) -> up to 32 waves/CU; gathers widened to
// 16B+8B per corner stream (18 loads/lane vs 27).
// XCD clustering kept: g&7 = XCD, each XCD owns 16 b's (49 blocks per b).
__global__ __launch_bounds__(256) void sample_attend(
    const float* __restrict__ Qf,            // fp32 q (if Qb16 == null)
    const unsigned short* __restrict__ Qb16, // bf16 q (preferred)
    const unsigned short* __restrict__ Kb,
    const unsigned short* __restrict__ Vb,
    const float* __restrict__ normx,
    const float* __restrict__ normy,
    const int* __restrict__ img_ids,
    const float* __restrict__ avgs,
    const float* __restrict__ stds,
    float* __restrict__ out)
{
    const unsigned g    = blockIdx.x;            // 0..6271
    const unsigned xcd  = g & 7;
    const unsigned slot = g >> 3;                // 0..783
    const int b = (int)(xcd * 16 + slot / 49);
    const int p = (int)((slot % 49) * 4 + (threadIdx.x >> 6));
    const int lane = threadIdx.x & 63;

    const size_t rowOff = ((size_t)b * 196 + p) * 768;
    const int d0 = lane * 8;                     // elems [d0, d0+8)
    const int d1 = 512 + lane * 4;               // elems [d1, d1+4)

    // ---- issue q loads first (independent of coord computation) ----
    float q[12];
    if (Qb16 != nullptr) {
        const shortx8 q16 = *(const shortx8*)&Qb16[rowOff + d0];
        const unsigned long long q8 = *(const unsigned long long*)&Qb16[rowOff + d1];
        #pragma unroll
        for (int e = 0; e < 8; e++) q[e] = bf2f((unsigned short)q16[e]);
        #pragma unroll
        for (int e = 0; e < 4; e++) q[8 + e] = bf2f((unsigned short)(q8 >> (16 * e)));
    } else {
        const floatx4 qa = *(const floatx4*)&Qf[rowOff + d0];
        const floatx4 qb2 = *(const floatx4*)&Qf[rowOff + d0 + 4];
        const floatx4 qc = *(const floatx4*)&Qf[rowOff + d1];
        #pragma unroll
        for (int e = 0; e < 4; e++) { q[e] = qa[e]; q[4 + e] = qb2[e]; q[8 + e] = qc[e]; }
    }

    const int id = img_ids[b];
    // grid flat = [sx(196), sy(196)]: gx = flat[2p], gy = flat[2p+1]
    auto coord = [&](int n) -> float {
        int c = 0;
        if (n >= 196) { n -= 196; c = 1; }
        const float base = (c == 0) ? normx[b * 196 + n] : normy[b * 196 + n];
        const float a = avgs[(size_t)id * 392 + c * 196 + n];
        const float s = stds[(size_t)id * 392 + c * 196 + n];
        return tanhf((base + a) * s);
    };
    const float gx = coord(2 * p);
    const float gy = coord(2 * p + 1);

    const float ix = ((gx + 1.0f) * 14.0f - 1.0f) * 0.5f;
    const float iy = ((gy + 1.0f) * 14.0f - 1.0f) * 0.5f;
    const float x0f = floorf(ix), y0f = floorf(iy);
    const float wx1 = ix - x0f, wx0 = 1.0f - wx1;
    const float wy1 = iy - y0f, wy0 = 1.0f - wy1;
    const int x0 = (int)x0f, y0 = (int)y0f;

    float cw[4]; int rr[4];
    {
        const int xs[4] = {x0, x0 + 1, x0, x0 + 1};
        const int ys[4] = {y0, y0, y0 + 1, y0 + 1};
        const float ws4[4] = {wx0 * wy0, wx1 * wy0, wx0 * wy1, wx1 * wy1};
        #pragma unroll
        for (int c = 0; c < 4; c++) {
            const bool valid = xs[c] >= 0 && xs[c] <= 13 && ys[c] >= 0 && ys[c] <= 13;
            cw[c] = valid ? ws4[c] : 0.0f;
            rr[c] = valid ? (ys[c] * 14 + xs[c]) * 768 : 0;
        }
    }

    const unsigned short* kb = Kb + (size_t)b * 196 * 768;
    const unsigned short* vb = Vb + (size_t)b * 196 * 768;

    // ---- gather all corner streams (independent loads, MLP-friendly) ----
    shortx8 k16[4], v16[4];
    unsigned long long k8[4], v8[4];
    #pragma unroll
    for (int c = 0; c < 4; c++) {
        k16[c] = *(const shortx8*)&kb[rr[c] + d0];
        v16[c] = *(const shortx8*)&vb[rr[c] + d0];
        k8[c]  = *(const unsigned long long*)&kb[rr[c] + d1];
        v8[c]  = *(const unsigned long long*)&vb[rr[c] + d1];
    }

    float kx[12] = {}, vx[12] = {};
    #pragma unroll
    for (int c = 0; c < 4; c++) {
        #pragma unroll
        for (int e = 0; e < 8; e++) {
            kx[e] += cw[c] * bf2f((unsigned short)k16[c][e]);
            vx[e] += cw[c] * bf2f((unsigned short)v16[c][e]);
        }
        #pragma unroll
        for (int e = 0; e < 4; e++) {
            kx[8 + e] += cw[c] * bf2f((unsigned short)(k8[c] >> (16 * e)));
            vx[8 + e] += cw[c] * bf2f((unsigned short)(v8[c] >> (16 * e)));
        }
    }

    float partial = 0.0f;
    #pragma unroll
    for (int e = 0; e < 12; e++) partial += kx[e] * q[e];

    #pragma unroll
    for (int off = 32; off >= 1; off >>= 1)
        partial += __shfl_xor(partial, off, 64);
    const float sig = 1.0f / (1.0f + expf(-0.01f * partial));

    floatx4 o0, o1, o2;
    #pragma unroll
    for (int e = 0; e < 4; e++) {
        o0[e] = sig * vx[e];
        o1[e] = sig * vx[4 + e];
        o2[e] = sig * vx[8 + e];
    }
    *(floatx4*)&out[rowOff + d0]     = o0;
    *(floatx4*)&out[rowOff + d0 + 4] = o1;
    *(floatx4*)&out[rowOff + d1]     = o2;
}

extern "C" void kernel_launch(void* const* d_in, const int* in_sizes, int n_in,
                              void* d_out, int out_size, void* d_ws, size_t ws_size,
                              hipStream_t stream) {
    const float* x     = (const float*)d_in[0];
    const int*   ids   = (const int*)d_in[1];
    // d_in[2] = mask (unused by reference)
    const float* normx = (const float*)d_in[3];
    const float* normy = (const float*)d_in[4];
    const float* Wq    = (const float*)d_in[5];
    const float* bq    = (const float*)d_in[6];
    const float* Wk    = (const float*)d_in[7];
    const float* bk    = (const float*)d_in[8];
    const float* Wv    = (const float*)d_in[9];
    const float* bv    = (const float*)d_in[10];
    const float* avgs  = (const float*)d_in[11];
    const float* stds  = (const float*)d_in[12];
    float* out = (float*)d_out;

    const int B = 128, P = 196, D = 768;
    const int M = B * P;                         // 25088
    const size_t qkvElems = (size_t)M * D;       // 19,267,584
    const size_t wElems   = (size_t)D * D;       // 589,824

    // ws tiers (deterministic: ws_size constant across calls)
    const size_t tierA = (4 * qkvElems + 3 * wElems) * 2;  // +bf16 q  (~157.7 MB)
    const size_t tierB = (3 * qkvElems + 3 * wElems) * 2;  // bf16 X/W/k/v (~119 MB)

    const int nSampBlocks = 8 * 16 * 49;         // 6272 (4 p per block)

    if (ws_size >= tierB) {
        unsigned short* Xb = (unsigned short*)d_ws;
        unsigned short* Wb = Xb + qkvElems;
        unsigned short* k  = Wb + 3 * wElems;
        unsigned short* v  = k + qkvElems;
        unsigned short* qb = (ws_size >= tierA) ? (v + qkvElems) : nullptr;
        float* qf = (qb == nullptr) ? out : nullptr;

        const int nbX = (int)(qkvElems / 8 / 256);   // 9408
        const int nbW = (int)(wElems / 8 / 256);     // 288
        cvt4<<<nbX + 3 * nbW, 256, 0, stream>>>(
            x, Wq, Wk, Wv, Xb, Wb, Wb + wElems, Wb + 2 * wElems, nbX, nbW, nbW);

        const int nGemmBlocks = (D / BN) * (M / BM) * 3;   // 3528 = 8*441
        gemm_qkv_bf16<<<nGemmBlocks, 256, 0, stream>>>(
            Xb, Wb, bq, bk, bv, qf, qb, k, v, M, D, D);

        sample_attend<<<nSampBlocks, 256, 0, stream>>>(
            qf, qb, k, v, normx, normy, ids, avgs, stds, out);
    } else {
        unsigned short* k = (unsigned short*)d_ws;
        unsigned short* v = k + qkvElems;

        dim3 gGemm(D / BN, M / BM, 3);
        gemm_qkv_f32<<<gGemm, 256, 0, stream>>>(
            x, Wq, Wk, Wv, bq, bk, bv, out, k, v, M, D, D);

        sample_attend<<<nSampBlocks, 256, 0, stream>>>(
            out, nullptr, k, v, normx, normy, ids, avgs, stds, out);
    }
}

// Round 4
// 330.347 us; speedup vs baseline: 1.0261x; 1.0119x over previous
//
#include <hip/hip_runtime.h>
#include <hip/hip_bf16.h>

typedef __attribute__((ext_vector_type(4))) float floatx4;
typedef __attribute__((ext_vector_type(8))) short shortx8;
typedef __attribute__((address_space(3))) void as3_void;
typedef const __attribute__((address_space(1))) void as1_void;

__device__ __forceinline__ unsigned short f2bf(float f) {
    unsigned int u; __builtin_memcpy(&u, &f, 4);
    u += 0x7FFFu + ((u >> 16) & 1u);   // RNE
    return (unsigned short)(u >> 16);
}
__device__ __forceinline__ float bf2f(unsigned short h) {
    unsigned int u = ((unsigned int)h) << 16;
    float f; __builtin_memcpy(&f, &u, 4); return f;
}
__device__ __forceinline__ shortx8 pack8(floatx4 lo, floatx4 hi) {
    shortx8 r;
    r[0] = (short)f2bf(lo[0]); r[1] = (short)f2bf(lo[1]);
    r[2] = (short)f2bf(lo[2]); r[3] = (short)f2bf(lo[3]);
    r[4] = (short)f2bf(hi[0]); r[5] = (short)f2bf(hi[1]);
    r[6] = (short)f2bf(hi[2]); r[7] = (short)f2bf(hi[3]);
    return r;
}
__device__ __forceinline__ void ld16(const unsigned short* g, unsigned short* l) {
    __builtin_amdgcn_global_load_lds((as1_void*)g, (as3_void*)l, 16, 0, 0);
}

#define BM 128
#define BN 128
#define BK 32

// ---------- fp32 -> bf16 pre-convert (4 segments in one launch) ----------
__global__ __launch_bounds__(256) void cvt4(
    const float* __restrict__ s0, const float* __restrict__ s1,
    const float* __restrict__ s2, const float* __restrict__ s3,
    unsigned short* __restrict__ d0, unsigned short* __restrict__ d1,
    unsigned short* __restrict__ d2, unsigned short* __restrict__ d3,
    int nb0, int nb1, int nb2)
{
    int bid = blockIdx.x;
    const float* s; unsigned short* d;
    if (bid < nb0)                  { s = s0; d = d0; }
    else if (bid < nb0 + nb1)       { s = s1; d = d1; bid -= nb0; }
    else if (bid < nb0 + nb1 + nb2) { s = s2; d = d2; bid -= nb0 + nb1; }
    else                            { s = s3; d = d3; bid -= nb0 + nb1 + nb2; }
    const size_t i = ((size_t)bid * 256 + threadIdx.x) * 8;
    const floatx4 lo = *(const floatx4*)(s + i);
    const floatx4 hi = *(const floatx4*)(s + i + 4);
    *(shortx8*)(d + i) = pack8(lo, hi);
}

// ---------- fast GEMM (round-1 proven 143us) + T2 chunk-XOR swizzle ----------
// q/k/v = Xb (MxK bf16) * Wb[z]^T (NxK bf16) + bias. 1D grid 3528 = 8*441;
// y-grouped XCD swizzle (FETCH 360->121 MB measured).
// T2: LDS slot `chunk` of row r holds global k-chunk `chunk ^ ((r>>1)&3)`.
// Staged via pre-swizzled GLOBAL column (LDS dest stays linear, rule 21);
// ds_read applies the same XOR. Per-quarter-wave 16B-slot distribution
// becomes uniform (2 lanes/slot) -> zero extra bank conflict (was 8 lanes
// on one 4-bank group = measured 1.08e7 conflict cycles).
__global__ __launch_bounds__(256) void gemm_qkv_bf16(
    const unsigned short* __restrict__ Xb,
    const unsigned short* __restrict__ Wb,   // 3 contiguous NxK mats
    const float* __restrict__ bq, const float* __restrict__ bk,
    const float* __restrict__ bv,
    float* __restrict__ Qf, unsigned short* __restrict__ Qb16,
    unsigned short* __restrict__ Kb, unsigned short* __restrict__ Vb,
    int M, int N, int K)
{
    __shared__ __attribute__((aligned(16))) unsigned short As[2 * BM * BK];
    __shared__ __attribute__((aligned(16))) unsigned short Bs[2 * BN * BK];

    // swizzled decode: w = y*18 + z*6 + x, chunked 441-per-XCD (bijective)
    const unsigned g    = blockIdx.x;
    const unsigned xcd  = g & 7u;
    const unsigned slot = g >> 3;                 // 0..440
    const unsigned w    = xcd * 441u + slot;      // y-grouped work index
    const unsigned yb   = w / 18u;                // M-tile 0..195
    const unsigned rr_  = w - yb * 18u;
    const unsigned z    = rr_ / 6u;               // 0..2
    const unsigned xb   = rr_ - z * 6u;           // N-tile 0..5

    const unsigned short* W = Wb + (size_t)z * N * K;
    const float* bias = (z == 0) ? bq : ((z == 1) ? bk : bv);

    const int tid  = threadIdx.x;
    const int wave = tid >> 6;
    const int lane = tid & 63;

    const int mBlock = (int)yb * BM;
    const int nBlock = (int)xb * BN;

    // staging: thread t -> row t>>2 (and +64). LDS dest slot = (t&3) linear;
    // GLOBAL column = ((t&3) ^ ((row>>1)&3)) * 8  (swizzle involution).
    // (row+64)>>1 & 3 == row>>1 & 3, so one sChunk serves both row loads.
    const int sRow   = tid >> 2;
    const int sChunk = ((tid & 3) ^ ((sRow >> 1) & 3)) * 8;
    const unsigned short* Ag = Xb + (size_t)(mBlock + sRow) * K + sChunk;
    const unsigned short* Bg = W  + (size_t)(nBlock + sRow) * K + sChunk;
    unsigned short* Al = &As[sRow * BK + (tid & 3) * 8];
    unsigned short* Bl = &Bs[sRow * BK + (tid & 3) * 8];

    floatx4 acc[4][4] = {};

    const int wm   = (wave >> 1) * 64;
    const int wn   = (wave & 1) * 64;
    const int fRow = lane & 15;
    // swizzled k-group slot: global chunk q lives in LDS slot q ^ ((row>>1)&3);
    // row = wm + i*16 + fRow and (wm + i*16) is 0 mod 8 -> bits = (fRow>>1)&3.
    const int fKs  = (((lane >> 4) ^ ((fRow >> 1) & 3))) * 8;

    for (int kt = 0; kt < K; kt += 2 * BK) {
        // chunk 0 (k = kt)
        ld16(Ag + kt,                      Al);
        ld16(Ag + kt + (size_t)64*K,       Al + 64 * BK);
        ld16(Bg + kt,                      Bl);
        ld16(Bg + kt + (size_t)64*K,       Bl + 64 * BK);
        // chunk 1 (k = kt + 32)
        ld16(Ag + kt + BK,                 Al + BM * BK);
        ld16(Ag + kt + BK + (size_t)64*K,  Al + BM * BK + 64 * BK);
        ld16(Bg + kt + BK,                 Bl + BN * BK);
        ld16(Bg + kt + BK + (size_t)64*K,  Bl + BN * BK + 64 * BK);
        __syncthreads();                    // drains vmcnt before barrier

        #pragma unroll
        for (int c = 0; c < 2; c++) {
            const unsigned short* Asc = As + c * BM * BK;
            const unsigned short* Bsc = Bs + c * BN * BK;
            shortx8 af[4], bfr[4];
            #pragma unroll
            for (int i = 0; i < 4; i++) {
                af[i]  = *(const shortx8*)&Asc[(wm + i*16 + fRow) * BK + fKs];
                bfr[i] = *(const shortx8*)&Bsc[(wn + i*16 + fRow) * BK + fKs];
            }
            #pragma unroll
            for (int i = 0; i < 4; i++)
                #pragma unroll
                for (int j = 0; j < 4; j++)
                    acc[i][j] = __builtin_amdgcn_mfma_f32_16x16x32_bf16(
                        af[i], bfr[j], acc[i][j], 0, 0, 0);
        }
        __syncthreads();                    // LDS reads done before next stage
    }

    // C/D layout: col = lane&15, row = (lane>>4)*4 + reg
    const int cRow = (lane >> 4) * 4;
    const int cCol = lane & 15;
    if (z == 0 && Qb16 == nullptr) {
        #pragma unroll
        for (int j = 0; j < 4; j++) {
            const int col = nBlock + wn + j*16 + cCol;
            const float bvf = bias[col];
            #pragma unroll
            for (int i = 0; i < 4; i++)
                #pragma unroll
                for (int r = 0; r < 4; r++)
                    Qf[(size_t)(mBlock + wm + i*16 + cRow + r) * N + col] =
                        acc[i][j][r] + bvf;
        }
    } else {
        unsigned short* Out = (z == 0) ? Qb16 : ((z == 1) ? Kb : Vb);
        #pragma unroll
        for (int j = 0; j < 4; j++) {
            const int col = nBlock + wn + j*16 + cCol;
            const float bvf = bias[col];
            #pragma unroll
            for (int i = 0; i < 4; i++)
                #pragma unroll
                for (int r = 0; r < 4; r++)
                    Out[(size_t)(mBlock + wm + i*16 + cRow + r) * N + col] =
                        f2bf(acc[i][j][r] + bvf);
        }
    }
}

// ---------- fallback GEMM (round-3 proven): fp32 src, pack in kernel ----------
__global__ __launch_bounds__(256) void gemm_qkv_f32(
    const float* __restrict__ X,
    const float* __restrict__ Wq, const float* __restrict__ Wk,
    const float* __restrict__ Wv,
    const float* __restrict__ bq, const float* __restrict__ bk,
    const float* __restrict__ bv,
    float* __restrict__ Qf, unsigned short* __restrict__ Kb,
    unsigned short* __restrict__ Vb,
    int M, int N, int K)
{
    __shared__ __attribute__((aligned(16))) unsigned short As[BM * BK];
    __shared__ __attribute__((aligned(16))) unsigned short Bs[BN * BK];

    const float* W;  const float* bias;
    if (blockIdx.z == 0)      { W = Wq; bias = bq; }
    else if (blockIdx.z == 1) { W = Wk; bias = bk; }
    else                      { W = Wv; bias = bv; }

    const int tid  = threadIdx.x;
    const int wave = tid >> 6;
    const int lane = tid & 63;
    const int mBlock = blockIdx.y * BM;
    const int nBlock = blockIdx.x * BN;

    const int sRow = tid >> 1;
    const int sCol = (tid & 1) * 16;
    const float* Ag = X + (size_t)(mBlock + sRow) * K + sCol;
    const float* Bg = W + (size_t)(nBlock + sRow) * K + sCol;
    unsigned short* Al = &As[sRow * BK + sCol];
    unsigned short* Bl = &Bs[sRow * BK + sCol];

    floatx4 acc[4][4] = {};
    const int wm   = (wave >> 1) * 64;
    const int wn   = (wave & 1) * 64;
    const int fRow = lane & 15;
    const int fK   = (lane >> 4) * 8;

    for (int kt = 0; kt < K; kt += BK) {
        floatx4 a[4], b[4];
        #pragma unroll
        for (int c = 0; c < 4; c++) {
            a[c] = *(const floatx4*)(Ag + kt + c * 4);
            b[c] = *(const floatx4*)(Bg + kt + c * 4);
        }
        __syncthreads();
        *(shortx8*)(Al)     = pack8(a[0], a[1]);
        *(shortx8*)(Al + 8) = pack8(a[2], a[3]);
        *(shortx8*)(Bl)     = pack8(b[0], b[1]);
        *(shortx8*)(Bl + 8) = pack8(b[2], b[3]);
        __syncthreads();

        shortx8 af[4], bfr[4];
        #pragma unroll
        for (int i = 0; i < 4; i++) {
            af[i]  = *(const shortx8*)&As[(wm + i*16 + fRow) * BK + fK];
            bfr[i] = *(const shortx8*)&Bs[(wn + i*16 + fRow) * BK + fK];
        }
        #pragma unroll
        for (int i = 0; i < 4; i++)
            #pragma unroll
            for (int j = 0; j < 4; j++)
                acc[i][j] = __builtin_amdgcn_mfma_f32_16x16x32_bf16(
                    af[i], bfr[j], acc[i][j], 0, 0, 0);
    }

    const int cRow = (lane >> 4) * 4;
    const int cCol = lane & 15;
    if (blockIdx.z == 0) {
        #pragma unroll
        for (int j = 0; j < 4; j++) {
            const int col = nBlock + wn + j*16 + cCol;
            const float bvf = bias[col];
            #pragma unroll
            for (int i = 0; i < 4; i++)
                #pragma unroll
                for (int r = 0; r < 4; r++)
                    Qf[(size_t)(mBlock + wm + i*16 + cRow + r) * N + col] =
                        acc[i][j][r] + bvf;
        }
    } else {
        unsigned short* Out = (blockIdx.z == 1) ? Kb : Vb;
        #pragma unroll
        for (int j = 0; j < 4; j++) {
            const int col = nBlock + wn + j*16 + cCol;
            const float bvf = bias[col];
            #pragma unroll
            for (int i = 0; i < 4; i++)
                #pragma unroll
                for (int r = 0; r < 4; r++)
                    Out[(size_t)(mBlock + wm + i*16 + cRow + r) * N + col] =
                        f2bf(acc[i][j][r] + bvf);
        }
    }
}

// ---------- sampler v2b: 4 waves/block, b walked DESCENDING per XCD ----------
// The gemm's per-XCD y-walk finishes on HIGH b's -> those k/v/q rows are
// L2-hot when the sampler launches. Walk b descending so the sampler's first
// blocks hit the warm lines before they're evicted.
__global__ __launch_bounds__(256) void sample_attend(
    const float* __restrict__ Qf,            // fp32 q (if Qb16 == null)
    const unsigned short* __restrict__ Qb16, // bf16 q (preferred)
    const unsigned short* __restrict__ Kb,
    const unsigned short* __restrict__ Vb,
    const float* __restrict__ normx,
    const float* __restrict__ normy,
    const int* __restrict__ img_ids,
    const float* __restrict__ avgs,
    const float* __restrict__ stds,
    float* __restrict__ out)
{
    const unsigned g    = blockIdx.x;            // 0..6271
    const unsigned xcd  = g & 7;
    const unsigned slot = g >> 3;                // 0..783
    const int b = (int)(xcd * 16 + (15 - slot / 49));
    const int p = (int)((slot % 49) * 4 + (threadIdx.x >> 6));
    const int lane = threadIdx.x & 63;

    const size_t rowOff = ((size_t)b * 196 + p) * 768;
    const int d0 = lane * 8;                     // elems [d0, d0+8)
    const int d1 = 512 + lane * 4;               // elems [d1, d1+4)

    // ---- issue q loads first (independent of coord computation) ----
    float q[12];
    if (Qb16 != nullptr) {
        const shortx8 q16 = *(const shortx8*)&Qb16[rowOff + d0];
        const unsigned long long q8 = *(const unsigned long long*)&Qb16[rowOff + d1];
        #pragma unroll
        for (int e = 0; e < 8; e++) q[e] = bf2f((unsigned short)q16[e]);
        #pragma unroll
        for (int e = 0; e < 4; e++) q[8 + e] = bf2f((unsigned short)(q8 >> (16 * e)));
    } else {
        const floatx4 qa = *(const floatx4*)&Qf[rowOff + d0];
        const floatx4 qb2 = *(const floatx4*)&Qf[rowOff + d0 + 4];
        const floatx4 qc = *(const floatx4*)&Qf[rowOff + d1];
        #pragma unroll
        for (int e = 0; e < 4; e++) { q[e] = qa[e]; q[4 + e] = qb2[e]; q[8 + e] = qc[e]; }
    }

    const int id = img_ids[b];
    // grid flat = [sx(196), sy(196)]: gx = flat[2p], gy = flat[2p+1]
    auto coord = [&](int n) -> float {
        int c = 0;
        if (n >= 196) { n -= 196; c = 1; }
        const float base = (c == 0) ? normx[b * 196 + n] : normy[b * 196 + n];
        const float a = avgs[(size_t)id * 392 + c * 196 + n];
        const float s = stds[(size_t)id * 392 + c * 196 + n];
        return tanhf((base + a) * s);
    };
    const float gx = coord(2 * p);
    const float gy = coord(2 * p + 1);

    const float ix = ((gx + 1.0f) * 14.0f - 1.0f) * 0.5f;
    const float iy = ((gy + 1.0f) * 14.0f - 1.0f) * 0.5f;
    const float x0f = floorf(ix), y0f = floorf(iy);
    const float wx1 = ix - x0f, wx0 = 1.0f - wx1;
    const float wy1 = iy - y0f, wy0 = 1.0f - wy1;
    const int x0 = (int)x0f, y0 = (int)y0f;

    float cw[4]; int rr[4];
    {
        const int xs[4] = {x0, x0 + 1, x0, x0 + 1};
        const int ys[4] = {y0, y0, y0 + 1, y0 + 1};
        const float ws4[4] = {wx0 * wy0, wx1 * wy0, wx0 * wy1, wx1 * wy1};
        #pragma unroll
        for (int c = 0; c < 4; c++) {
            const bool valid = xs[c] >= 0 && xs[c] <= 13 && ys[c] >= 0 && ys[c] <= 13;
            cw[c] = valid ? ws4[c] : 0.0f;
            rr[c] = valid ? (ys[c] * 14 + xs[c]) * 768 : 0;
        }
    }

    const unsigned short* kb = Kb + (size_t)b * 196 * 768;
    const unsigned short* vb = Vb + (size_t)b * 196 * 768;

    // ---- gather all corner streams (independent loads, MLP-friendly) ----
    shortx8 k16[4], v16[4];
    unsigned long long k8[4], v8[4];
    #pragma unroll
    for (int c = 0; c < 4; c++) {
        k16[c] = *(const shortx8*)&kb[rr[c] + d0];
        v16[c] = *(const shortx8*)&vb[rr[c] + d0];
        k8[c]  = *(const unsigned long long*)&kb[rr[c] + d1];
        v8[c]  = *(const unsigned long long*)&vb[rr[c] + d1];
    }

    float kx[12] = {}, vx[12] = {};
    #pragma unroll
    for (int c = 0; c < 4; c++) {
        #pragma unroll
        for (int e = 0; e < 8; e++) {
            kx[e] += cw[c] * bf2f((unsigned short)k16[c][e]);
            vx[e] += cw[c] * bf2f((unsigned short)v16[c][e]);
        }
        #pragma unroll
        for (int e = 0; e < 4; e++) {
            kx[8 + e] += cw[c] * bf2f((unsigned short)(k8[c] >> (16 * e)));
            vx[8 + e] += cw[c] * bf2f((unsigned short)(v8[c] >> (16 * e)));
        }
    }

    float partial = 0.0f;
    #pragma unroll
    for (int e = 0; e < 12; e++) partial += kx[e] * q[e];

    #pragma unroll
    for (int off = 32; off >= 1; off >>= 1)
        partial += __shfl_xor(partial, off, 64);
    const float sig = 1.0f / (1.0f + expf(-0.01f * partial));

    floatx4 o0, o1, o2;
    #pragma unroll
    for (int e = 0; e < 4; e++) {
        o0[e] = sig * vx[e];
        o1[e] = sig * vx[4 + e];
        o2[e] = sig * vx[8 + e];
    }
    *(floatx4*)&out[rowOff + d0]     = o0;
    *(floatx4*)&out[rowOff + d0 + 4] = o1;
    *(floatx4*)&out[rowOff + d1]     = o2;
}

extern "C" void kernel_launch(void* const* d_in, const int* in_sizes, int n_in,
                              void* d_out, int out_size, void* d_ws, size_t ws_size,
                              hipStream_t stream) {
    const float* x     = (const float*)d_in[0];
    const int*   ids   = (const int*)d_in[1];
    // d_in[2] = mask (unused by reference)
    const float* normx = (const float*)d_in[3];
    const float* normy = (const float*)d_in[4];
    const float* Wq    = (const float*)d_in[5];
    const float* bq    = (const float*)d_in[6];
    const float* Wk    = (const float*)d_in[7];
    const float* bk    = (const float*)d_in[8];
    const float* Wv    = (const float*)d_in[9];
    const float* bv    = (const float*)d_in[10];
    const float* avgs  = (const float*)d_in[11];
    const float* stds  = (const float*)d_in[12];
    float* out = (float*)d_out;

    const int B = 128, P = 196, D = 768;
    const int M = B * P;                         // 25088
    const size_t qkvElems = (size_t)M * D;       // 19,267,584
    const size_t wElems   = (size_t)D * D;       // 589,824

    // ws tiers (deterministic: ws_size constant across calls)
    const size_t tierA = (4 * qkvElems + 3 * wElems) * 2;  // +bf16 q  (~157.7 MB)
    const size_t tierB = (3 * qkvElems + 3 * wElems) * 2;  // bf16 X/W/k/v (~119 MB)

    const int nSampBlocks = 8 * 16 * 49;         // 6272 (4 p per block)

    if (ws_size >= tierB) {
        unsigned short* Xb = (unsigned short*)d_ws;
        unsigned short* Wb = Xb + qkvElems;
        unsigned short* k  = Wb + 3 * wElems;
        unsigned short* v  = k + qkvElems;
        unsigned short* qb = (ws_size >= tierA) ? (v + qkvElems) : nullptr;
        float* qf = (qb == nullptr) ? out : nullptr;

        const int nbX = (int)(qkvElems / 8 / 256);   // 9408
        const int nbW = (int)(wElems / 8 / 256);     // 288
        cvt4<<<nbX + 3 * nbW, 256, 0, stream>>>(
            x, Wq, Wk, Wv, Xb, Wb, Wb + wElems, Wb + 2 * wElems, nbX, nbW, nbW);

        const int nGemmBlocks = (D / BN) * (M / BM) * 3;   // 3528 = 8*441
        gemm_qkv_bf16<<<nGemmBlocks, 256, 0, stream>>>(
            Xb, Wb, bq, bk, bv, qf, qb, k, v, M, D, D);

        sample_attend<<<nSampBlocks, 256, 0, stream>>>(
            qf, qb, k, v, normx, normy, ids, avgs, stds, out);
    } else {
        unsigned short* k = (unsigned short*)d_ws;
        unsigned short* v = k + qkvElems;

        dim3 gGemm(D / BN, M / BM, 3);
        gemm_qkv_f32<<<gGemm, 256, 0, stream>>>(
            x, Wq, Wk, Wv, bq, bk, bv, out, k, v, M, D, D);

        sample_attend<<<nSampBlocks, 256, 0, stream>>>(
            out, nullptr, k, v, normx, normy, ids, avgs, stds, out);
    }
}

// Round 5
// 326.952 us; speedup vs baseline: 1.0368x; 1.0104x over previous
//
#include <hip/hip_runtime.h>
#include <hip/hip_bf16.h>

typedef __attribute__((ext_vector_type(4))) float floatx4;
typedef __attribute__((ext_vector_type(8))) short shortx8;
typedef __attribute__((address_space(3))) void as3_void;
typedef const __attribute__((address_space(1))) void as1_void;

__device__ __forceinline__ unsigned short f2bf(float f) {
    unsigned int u; __builtin_memcpy(&u, &f, 4);
    u += 0x7FFFu + ((u >> 16) & 1u);   // RNE
    return (unsigned short)(u >> 16);
}
__device__ __forceinline__ float bf2f(unsigned short h) {
    unsigned int u = ((unsigned int)h) << 16;
    float f; __builtin_memcpy(&f, &u, 4); return f;
}
__device__ __forceinline__ shortx8 pack8(floatx4 lo, floatx4 hi) {
    shortx8 r;
    r[0] = (short)f2bf(lo[0]); r[1] = (short)f2bf(lo[1]);
    r[2] = (short)f2bf(lo[2]); r[3] = (short)f2bf(lo[3]);
    r[4] = (short)f2bf(hi[0]); r[5] = (short)f2bf(hi[1]);
    r[6] = (short)f2bf(hi[2]); r[7] = (short)f2bf(hi[3]);
    return r;
}
__device__ __forceinline__ void ld16(const unsigned short* g, unsigned short* l) {
    __builtin_amdgcn_global_load_lds((as1_void*)g, (as3_void*)l, 16, 0, 0);
}

#define BM 128
#define BN 128
#define BK 32

// ---------- fp32 -> bf16 pre-convert (4 segments in one launch) ----------
__global__ __launch_bounds__(256) void cvt4(
    const float* __restrict__ s0, const float* __restrict__ s1,
    const float* __restrict__ s2, const float* __restrict__ s3,
    unsigned short* __restrict__ d0, unsigned short* __restrict__ d1,
    unsigned short* __restrict__ d2, unsigned short* __restrict__ d3,
    int nb0, int nb1, int nb2)
{
    int bid = blockIdx.x;
    const float* s; unsigned short* d;
    if (bid < nb0)                  { s = s0; d = d0; }
    else if (bid < nb0 + nb1)       { s = s1; d = d1; bid -= nb0; }
    else if (bid < nb0 + nb1 + nb2) { s = s2; d = d2; bid -= nb0 + nb1; }
    else                            { s = s3; d = d3; bid -= nb0 + nb1 + nb2; }
    const size_t i = ((size_t)bid * 256 + threadIdx.x) * 8;
    const floatx4 lo = *(const floatx4*)(s + i);
    const floatx4 hi = *(const floatx4*)(s + i + 4);
    *(shortx8*)(d + i) = pack8(lo, hi);
}

// ---------- fast GEMM v3: minimal-2-phase pipeline (catalog T3 recipe) ----
// q/k/v = Xb (MxK bf16) * Wb[z]^T (NxK bf16) + bias. 1D grid 3528 = 8*441;
// y-grouped XCD swizzle (FETCH 360->121 MB measured, round 1).
// Round-4 lesson (T2 gate confirmed): LDS bank conflicts are HIDDEN in this
// schedule (conflicts 1.08e7->0 made it SLOWER via staging-coalescing loss)
// -> linear LDS addressing restored.
// v3 change: true LDS double-buffer + stage-ahead. Old loop exposed the full
// staging latency every iter (stage -> drain -> compute). New loop:
//   stage(t+1, buf^1)  [8 global_load_lds issued first]
//   compute(t, buf)    [16 ds_read_b128 + 32 MFMA  ~ hides the load latency]
//   __syncthreads()    [= vmcnt(0)+barrier; loads had the whole compute to land]
// One barrier per K-tile (was 2), staging overlapped with compute.
__global__ __launch_bounds__(256) void gemm_qkv_bf16(
    const unsigned short* __restrict__ Xb,
    const unsigned short* __restrict__ Wb,   // 3 contiguous NxK mats
    const float* __restrict__ bq, const float* __restrict__ bk,
    const float* __restrict__ bv,
    float* __restrict__ Qf, unsigned short* __restrict__ Qb16,
    unsigned short* __restrict__ Kb, unsigned short* __restrict__ Vb,
    int M, int N, int K)
{
    // [buf][chunk(2) x BM x BK] : 2 x 16 KiB per matrix = 64 KiB total
    __shared__ __attribute__((aligned(16))) unsigned short As[2][2 * BM * BK];
    __shared__ __attribute__((aligned(16))) unsigned short Bs[2][2 * BN * BK];

    // swizzled decode: w = y*18 + z*6 + x, chunked 441-per-XCD (bijective)
    const unsigned g    = blockIdx.x;
    const unsigned xcd  = g & 7u;
    const unsigned slot = g >> 3;                 // 0..440
    const unsigned w    = xcd * 441u + slot;      // y-grouped work index
    const unsigned yb   = w / 18u;                // M-tile 0..195
    const unsigned rr_  = w - yb * 18u;
    const unsigned z    = rr_ / 6u;               // 0..2
    const unsigned xb   = rr_ - z * 6u;           // N-tile 0..5

    const unsigned short* W = Wb + (size_t)z * N * K;
    const float* bias = (z == 0) ? bq : ((z == 1) ? bk : bv);

    const int tid  = threadIdx.x;
    const int wave = tid >> 6;
    const int lane = tid & 63;

    const int mBlock = (int)yb * BM;
    const int nBlock = (int)xb * BN;

    // staging: thread t -> row t>>2 (and +64), 8-elem chunk (t&3)*8.
    // LDS dest elem offset = tid*8 (wave-uniform base + lane*16B) ✓
    const int sRow   = tid >> 2;
    const int sChunk = (tid & 3) * 8;
    const unsigned short* Ag = Xb + (size_t)(mBlock + sRow) * K + sChunk;
    const unsigned short* Bg = W  + (size_t)(nBlock + sRow) * K + sChunk;
    const int ldsOff = sRow * BK + sChunk;        // == tid*8, linear

    floatx4 acc[4][4] = {};

    const int wm   = (wave >> 1) * 64;
    const int wn   = (wave & 1) * 64;
    const int fRow = lane & 15;
    const int fK   = (lane >> 4) * 8;

    const int NT = K / (2 * BK);                  // 12 K-tiles of 64

    // ---- prologue: stage tile 0 into buf 0, drain, barrier ----
    {
        unsigned short* Al = &As[0][ldsOff];
        unsigned short* Bl = &Bs[0][ldsOff];
        ld16(Ag,                      Al);
        ld16(Ag + (size_t)64*K,       Al + 64 * BK);
        ld16(Bg,                      Bl);
        ld16(Bg + (size_t)64*K,       Bl + 64 * BK);
        ld16(Ag + BK,                 Al + BM * BK);
        ld16(Ag + BK + (size_t)64*K,  Al + BM * BK + 64 * BK);
        ld16(Bg + BK,                 Bl + BN * BK);
        ld16(Bg + BK + (size_t)64*K,  Bl + BN * BK + 64 * BK);
    }
    __syncthreads();

    for (int t = 0; t < NT; ++t) {
        // ---- issue next tile's staging FIRST (lands during compute) ----
        if (t + 1 < NT) {
            const int kt = (t + 1) * 2 * BK;
            unsigned short* Al = &As[(t + 1) & 1][ldsOff];
            unsigned short* Bl = &Bs[(t + 1) & 1][ldsOff];
            ld16(Ag + kt,                      Al);
            ld16(Ag + kt + (size_t)64*K,       Al + 64 * BK);
            ld16(Bg + kt,                      Bl);
            ld16(Bg + kt + (size_t)64*K,       Bl + 64 * BK);
            ld16(Ag + kt + BK,                 Al + BM * BK);
            ld16(Ag + kt + BK + (size_t)64*K,  Al + BM * BK + 64 * BK);
            ld16(Bg + kt + BK,                 Bl + BN * BK);
            ld16(Bg + kt + BK + (size_t)64*K,  Bl + BN * BK + 64 * BK);
        }

        // ---- compute current tile from buf[t&1] ----
        const unsigned short* Ab = As[t & 1];
        const unsigned short* Bb = Bs[t & 1];
        #pragma unroll
        for (int c = 0; c < 2; c++) {
            const unsigned short* Asc = Ab + c * BM * BK;
            const unsigned short* Bsc = Bb + c * BN * BK;
            shortx8 af[4], bfr[4];
            #pragma unroll
            for (int i = 0; i < 4; i++) {
                af[i]  = *(const shortx8*)&Asc[(wm + i*16 + fRow) * BK + fK];
                bfr[i] = *(const shortx8*)&Bsc[(wn + i*16 + fRow) * BK + fK];
            }
            #pragma unroll
            for (int i = 0; i < 4; i++)
                #pragma unroll
                for (int j = 0; j < 4; j++)
                    acc[i][j] = __builtin_amdgcn_mfma_f32_16x16x32_bf16(
                        af[i], bfr[j], acc[i][j], 0, 0, 0);
        }
        __syncthreads();   // vmcnt(0)+barrier: next tile staged, reads done
    }

    // C/D layout: col = lane&15, row = (lane>>4)*4 + reg
    const int cRow = (lane >> 4) * 4;
    const int cCol = lane & 15;
    if (z == 0 && Qb16 == nullptr) {
        #pragma unroll
        for (int j = 0; j < 4; j++) {
            const int col = nBlock + wn + j*16 + cCol;
            const float bvf = bias[col];
            #pragma unroll
            for (int i = 0; i < 4; i++)
                #pragma unroll
                for (int r = 0; r < 4; r++)
                    Qf[(size_t)(mBlock + wm + i*16 + cRow + r) * N + col] =
                        acc[i][j][r] + bvf;
        }
    } else {
        unsigned short* Out = (z == 0) ? Qb16 : ((z == 1) ? Kb : Vb);
        #pragma unroll
        for (int j = 0; j < 4; j++) {
            const int col = nBlock + wn + j*16 + cCol;
            const float bvf = bias[col];
            #pragma unroll
            for (int i = 0; i < 4; i++)
                #pragma unroll
                for (int r = 0; r < 4; r++)
                    Out[(size_t)(mBlock + wm + i*16 + cRow + r) * N + col] =
                        f2bf(acc[i][j][r] + bvf);
        }
    }
}

// ---------- fallback GEMM (round-3 proven): fp32 src, pack in kernel ----------
__global__ __launch_bounds__(256) void gemm_qkv_f32(
    const float* __restrict__ X,
    const float* __restrict__ Wq, const float* __restrict__ Wk,
    const float* __restrict__ Wv,
    const float* __restrict__ bq, const float* __restrict__ bk,
    const float* __restrict__ bv,
    float* __restrict__ Qf, unsigned short* __restrict__ Kb,
    unsigned short* __restrict__ Vb,
    int M, int N, int K)
{
    __shared__ __attribute__((aligned(16))) unsigned short As[BM * BK];
    __shared__ __attribute__((aligned(16))) unsigned short Bs[BN * BK];

    const float* W;  const float* bias;
    if (blockIdx.z == 0)      { W = Wq; bias = bq; }
    else if (blockIdx.z == 1) { W = Wk; bias = bk; }
    else                      { W = Wv; bias = bv; }

    const int tid  = threadIdx.x;
    const int wave = tid >> 6;
    const int lane = tid & 63;
    const int mBlock = blockIdx.y * BM;
    const int nBlock = blockIdx.x * BN;

    const int sRow = tid >> 1;
    const int sCol = (tid & 1) * 16;
    const float* Ag = X + (size_t)(mBlock + sRow) * K + sCol;
    const float* Bg = W + (size_t)(nBlock + sRow) * K + sCol;
    unsigned short* Al = &As[sRow * BK + sCol];
    unsigned short* Bl = &Bs[sRow * BK + sCol];

    floatx4 acc[4][4] = {};
    const int wm   = (wave >> 1) * 64;
    const int wn   = (wave & 1) * 64;
    const int fRow = lane & 15;
    const int fK   = (lane >> 4) * 8;

    for (int kt = 0; kt < K; kt += BK) {
        floatx4 a[4], b[4];
        #pragma unroll
        for (int c = 0; c < 4; c++) {
            a[c] = *(const floatx4*)(Ag + kt + c * 4);
            b[c] = *(const floatx4*)(Bg + kt + c * 4);
        }
        __syncthreads();
        *(shortx8*)(Al)     = pack8(a[0], a[1]);
        *(shortx8*)(Al + 8) = pack8(a[2], a[3]);
        *(shortx8*)(Bl)     = pack8(b[0], b[1]);
        *(shortx8*)(Bl + 8) = pack8(b[2], b[3]);
        __syncthreads();

        shortx8 af[4], bfr[4];
        #pragma unroll
        for (int i = 0; i < 4; i++) {
            af[i]  = *(const shortx8*)&As[(wm + i*16 + fRow) * BK + fK];
            bfr[i] = *(const shortx8*)&Bs[(wn + i*16 + fRow) * BK + fK];
        }
        #pragma unroll
        for (int i = 0; i < 4; i++)
            #pragma unroll
            for (int j = 0; j < 4; j++)
                acc[i][j] = __builtin_amdgcn_mfma_f32_16x16x32_bf16(
                    af[i], bfr[j], acc[i][j], 0, 0, 0);
    }

    const int cRow = (lane >> 4) * 4;
    const int cCol = lane & 15;
    if (blockIdx.z == 0) {
        #pragma unroll
        for (int j = 0; j < 4; j++) {
            const int col = nBlock + wn + j*16 + cCol;
            const float bvf = bias[col];
            #pragma unroll
            for (int i = 0; i < 4; i++)
                #pragma unroll
                for (int r = 0; r < 4; r++)
                    Qf[(size_t)(mBlock + wm + i*16 + cRow + r) * N + col] =
                        acc[i][j][r] + bvf;
        }
    } else {
        unsigned short* Out = (blockIdx.z == 1) ? Kb : Vb;
        #pragma unroll
        for (int j = 0; j < 4; j++) {
            const int col = nBlock + wn + j*16 + cCol;
            const float bvf = bias[col];
            #pragma unroll
            for (int i = 0; i < 4; i++)
                #pragma unroll
                for (int r = 0; r < 4; r++)
                    Out[(size_t)(mBlock + wm + i*16 + cRow + r) * N + col] =
                        f2bf(acc[i][j][r] + bvf);
        }
    }
}

// ---------- sampler v2b: 4 waves/block, b walked DESCENDING per XCD ----------
// The gemm's per-XCD y-walk finishes on HIGH b's -> those k/v/q rows are
// L2-hot when the sampler launches ("rest" time 191->180us w/ this change).
__global__ __launch_bounds__(256) void sample_attend(
    const float* __restrict__ Qf,            // fp32 q (if Qb16 == null)
    const unsigned short* __restrict__ Qb16, // bf16 q (preferred)
    const unsigned short* __restrict__ Kb,
    const unsigned short* __restrict__ Vb,
    const float* __restrict__ normx,
    const float* __restrict__ normy,
    const int* __restrict__ img_ids,
    const float* __restrict__ avgs,
    const float* __restrict__ stds,
    float* __restrict__ out)
{
    const unsigned g    = blockIdx.x;            // 0..6271
    const unsigned xcd  = g & 7;
    const unsigned slot = g >> 3;                // 0..783
    const int b = (int)(xcd * 16 + (15 - slot / 49));
    const int p = (int)((slot % 49) * 4 + (threadIdx.x >> 6));
    const int lane = threadIdx.x & 63;

    const size_t rowOff = ((size_t)b * 196 + p) * 768;
    const int d0 = lane * 8;                     // elems [d0, d0+8)
    const int d1 = 512 + lane * 4;               // elems [d1, d1+4)

    // ---- issue q loads first (independent of coord computation) ----
    float q[12];
    if (Qb16 != nullptr) {
        const shortx8 q16 = *(const shortx8*)&Qb16[rowOff + d0];
        const unsigned long long q8 = *(const unsigned long long*)&Qb16[rowOff + d1];
        #pragma unroll
        for (int e = 0; e < 8; e++) q[e] = bf2f((unsigned short)q16[e]);
        #pragma unroll
        for (int e = 0; e < 4; e++) q[8 + e] = bf2f((unsigned short)(q8 >> (16 * e)));
    } else {
        const floatx4 qa = *(const floatx4*)&Qf[rowOff + d0];
        const floatx4 qb2 = *(const floatx4*)&Qf[rowOff + d0 + 4];
        const floatx4 qc = *(const floatx4*)&Qf[rowOff + d1];
        #pragma unroll
        for (int e = 0; e < 4; e++) { q[e] = qa[e]; q[4 + e] = qb2[e]; q[8 + e] = qc[e]; }
    }

    const int id = img_ids[b];
    // grid flat = [sx(196), sy(196)]: gx = flat[2p], gy = flat[2p+1]
    auto coord = [&](int n) -> float {
        int c = 0;
        if (n >= 196) { n -= 196; c = 1; }
        const float base = (c == 0) ? normx[b * 196 + n] : normy[b * 196 + n];
        const float a = avgs[(size_t)id * 392 + c * 196 + n];
        const float s = stds[(size_t)id * 392 + c * 196 + n];
        return tanhf((base + a) * s);
    };
    const float gx = coord(2 * p);
    const float gy = coord(2 * p + 1);

    const float ix = ((gx + 1.0f) * 14.0f - 1.0f) * 0.5f;
    const float iy = ((gy + 1.0f) * 14.0f - 1.0f) * 0.5f;
    const float x0f = floorf(ix), y0f = floorf(iy);
    const float wx1 = ix - x0f, wx0 = 1.0f - wx1;
    const float wy1 = iy - y0f, wy0 = 1.0f - wy1;
    const int x0 = (int)x0f, y0 = (int)y0f;

    float cw[4]; int rr[4];
    {
        const int xs[4] = {x0, x0 + 1, x0, x0 + 1};
        const int ys[4] = {y0, y0, y0 + 1, y0 + 1};
        const float ws4[4] = {wx0 * wy0, wx1 * wy0, wx0 * wy1, wx1 * wy1};
        #pragma unroll
        for (int c = 0; c < 4; c++) {
            const bool valid = xs[c] >= 0 && xs[c] <= 13 && ys[c] >= 0 && ys[c] <= 13;
            cw[c] = valid ? ws4[c] : 0.0f;
            rr[c] = valid ? (ys[c] * 14 + xs[c]) * 768 : 0;
        }
    }

    const unsigned short* kb = Kb + (size_t)b * 196 * 768;
    const unsigned short* vb = Vb + (size_t)b * 196 * 768;

    // ---- gather all corner streams (independent loads, MLP-friendly) ----
    shortx8 k16[4], v16[4];
    unsigned long long k8[4], v8[4];
    #pragma unroll
    for (int c = 0; c < 4; c++) {
        k16[c] = *(const shortx8*)&kb[rr[c] + d0];
        v16[c] = *(const shortx8*)&vb[rr[c] + d0];
        k8[c]  = *(const unsigned long long*)&kb[rr[c] + d1];
        v8[c]  = *(const unsigned long long*)&vb[rr[c] + d1];
    }

    float kx[12] = {}, vx[12] = {};
    #pragma unroll
    for (int c = 0; c < 4; c++) {
        #pragma unroll
        for (int e = 0; e < 8; e++) {
            kx[e] += cw[c] * bf2f((unsigned short)k16[c][e]);
            vx[e] += cw[c] * bf2f((unsigned short)v16[c][e]);
        }
        #pragma unroll
        for (int e = 0; e < 4; e++) {
            kx[8 + e] += cw[c] * bf2f((unsigned short)(k8[c] >> (16 * e)));
            vx[8 + e] += cw[c] * bf2f((unsigned short)(v8[c] >> (16 * e)));
        }
    }

    float partial = 0.0f;
    #pragma unroll
    for (int e = 0; e < 12; e++) partial += kx[e] * q[e];

    #pragma unroll
    for (int off = 32; off >= 1; off >>= 1)
        partial += __shfl_xor(partial, off, 64);
    const float sig = 1.0f / (1.0f + expf(-0.01f * partial));

    floatx4 o0, o1, o2;
    #pragma unroll
    for (int e = 0; e < 4; e++) {
        o0[e] = sig * vx[e];
        o1[e] = sig * vx[4 + e];
        o2[e] = sig * vx[8 + e];
    }
    *(floatx4*)&out[rowOff + d0]     = o0;
    *(floatx4*)&out[rowOff + d0 + 4] = o1;
    *(floatx4*)&out[rowOff + d1]     = o2;
}

extern "C" void kernel_launch(void* const* d_in, const int* in_sizes, int n_in,
                              void* d_out, int out_size, void* d_ws, size_t ws_size,
                              hipStream_t stream) {
    const float* x     = (const float*)d_in[0];
    const int*   ids   = (const int*)d_in[1];
    // d_in[2] = mask (unused by reference)
    const float* normx = (const float*)d_in[3];
    const float* normy = (const float*)d_in[4];
    const float* Wq    = (const float*)d_in[5];
    const float* bq    = (const float*)d_in[6];
    const float* Wk    = (const float*)d_in[7];
    const float* bk    = (const float*)d_in[8];
    const float* Wv    = (const float*)d_in[9];
    const float* bv    = (const float*)d_in[10];
    const float* avgs  = (const float*)d_in[11];
    const float* stds  = (const float*)d_in[12];
    float* out = (float*)d_out;

    const int B = 128, P = 196, D = 768;
    const int M = B * P;                         // 25088
    const size_t qkvElems = (size_t)M * D;       // 19,267,584
    const size_t wElems   = (size_t)D * D;       // 589,824

    // ws tiers (deterministic: ws_size constant across calls)
    const size_t tierA = (4 * qkvElems + 3 * wElems) * 2;  // +bf16 q  (~157.7 MB)
    const size_t tierB = (3 * qkvElems + 3 * wElems) * 2;  // bf16 X/W/k/v (~119 MB)

    const int nSampBlocks = 8 * 16 * 49;         // 6272 (4 p per block)

    if (ws_size >= tierB) {
        unsigned short* Xb = (unsigned short*)d_ws;
        unsigned short* Wb = Xb + qkvElems;
        unsigned short* k  = Wb + 3 * wElems;
        unsigned short* v  = k + qkvElems;
        unsigned short* qb = (ws_size >= tierA) ? (v + qkvElems) : nullptr;
        float* qf = (qb == nullptr) ? out : nullptr;

        const int nbX = (int)(qkvElems / 8 / 256);   // 9408
        const int nbW = (int)(wElems / 8 / 256);     // 288
        cvt4<<<nbX + 3 * nbW, 256, 0, stream>>>(
            x, Wq, Wk, Wv, Xb, Wb, Wb + wElems, Wb + 2 * wElems, nbX, nbW, nbW);

        const int nGemmBlocks = (D / BN) * (M / BM) * 3;   // 3528 = 8*441
        gemm_qkv_bf16<<<nGemmBlocks, 256, 0, stream>>>(
            Xb, Wb, bq, bk, bv, qf, qb, k, v, M, D, D);

        sample_attend<<<nSampBlocks, 256, 0, stream>>>(
            qf, qb, k, v, normx, normy, ids, avgs, stds, out);
    } else {
        unsigned short* k = (unsigned short*)d_ws;
        unsigned short* v = k + qkvElems;

        dim3 gGemm(D / BN, M / BM, 3);
        gemm_qkv_f32<<<gGemm, 256, 0, stream>>>(
            x, Wq, Wk, Wv, bq, bk, bv, out, k, v, M, D, D);

        sample_attend<<<nSampBlocks, 256, 0, stream>>>(
            out, nullptr, k, v, normx, normy, ids, avgs, stds, out);
    }
}